// Round 1
// baseline (317.362 us; speedup 1.0000x reference)
//
#include <hip/hip_runtime.h>

#define S_LEN 2048
#define D_DIM 128
#define QB    64
#define NT    32
#define NWAVES 4

typedef __attribute__((ext_vector_type(8))) short short8;
typedef __attribute__((ext_vector_type(4))) float f32x4;

__device__ __forceinline__ unsigned short f2bf(float f) {
  union { float f; unsigned int u; } x;
  x.f = f;
  x.u += 0x7FFFu + ((x.u >> 16) & 1u);   // round-to-nearest-even
  return (unsigned short)(x.u >> 16);
}

__global__ __launch_bounds__(256)
void attn_fwd(const float* __restrict__ Qg, const float* __restrict__ Kg,
              const float* __restrict__ Vg, float* __restrict__ Og) {
  // K tile: row-major [NT][D], bf16, XOR-swizzled by ((row&7)<<4) on 16B chunks
  __shared__ __attribute__((aligned(16))) unsigned short Ks[NT * D_DIM];
  // V tile: transposed [D][NT] bf16 so PV B-frag is one contiguous b128
  __shared__ __attribute__((aligned(16))) unsigned short Vt[D_DIM * NT];
  // per-wave P transpose buffer [16][NT]
  __shared__ __attribute__((aligned(16))) unsigned short Ps[NWAVES][16 * NT];

  const int tid  = threadIdx.x;
  const int wid  = tid >> 6;
  const int lane = tid & 63;
  const int lg   = lane >> 4;   // 0..3
  const int ll   = lane & 15;   // 0..15

  const int nqt = S_LEN / QB;               // 32 q-tiles per (b,h)
  const int bh  = blockIdx.x / nqt;
  const int qt  = blockIdx.x % nqt;
  const size_t base = (size_t)bh * S_LEN * D_DIM;

  const float scale = 0.08838834764831845f; // 1/sqrt(128)

  // ---- Q fragments in registers: A-layout row=ll, k = c*32 + lg*8 + e ----
  short8 qa[4];
  {
    const float* qp = Qg + base + (size_t)(qt * QB + wid * 16 + ll) * D_DIM;
#pragma unroll
    for (int c = 0; c < 4; ++c) {
      const float4* p4 = (const float4*)(qp + c * 32 + lg * 8);
      float4 x0 = p4[0], x1 = p4[1];
      short8 a;
      a[0] = (short)f2bf(x0.x * scale);
      a[1] = (short)f2bf(x0.y * scale);
      a[2] = (short)f2bf(x0.z * scale);
      a[3] = (short)f2bf(x0.w * scale);
      a[4] = (short)f2bf(x1.x * scale);
      a[5] = (short)f2bf(x1.y * scale);
      a[6] = (short)f2bf(x1.z * scale);
      a[7] = (short)f2bf(x1.w * scale);
      qa[c] = a;
    }
  }

  const f32x4 zacc = {0.f, 0.f, 0.f, 0.f};
  f32x4 acc[8];
#pragma unroll
  for (int i = 0; i < 8; ++i) acc[i] = zacc;
  float mrow[4] = {-1e30f, -1e30f, -1e30f, -1e30f};
  float lrow[4] = {0.f, 0.f, 0.f, 0.f};

  for (int t = 0; t < S_LEN / NT; ++t) {
    __syncthreads();   // previous tile's compute done before restaging

    // ---- stage K tile: thread covers 16 cols of one row ----
    {
      const int r  = tid >> 3;          // 0..31
      const int c0 = (tid & 7) << 4;    // 0,16,..,112
      const float4* kp = (const float4*)(Kg + base + (size_t)(t * NT + r) * D_DIM + c0);
      float4 x0 = kp[0], x1 = kp[1], x2 = kp[2], x3 = kp[3];
      uint4 u0, u1;
      u0.x = (unsigned)f2bf(x0.x) | ((unsigned)f2bf(x0.y) << 16);
      u0.y = (unsigned)f2bf(x0.z) | ((unsigned)f2bf(x0.w) << 16);
      u0.z = (unsigned)f2bf(x1.x) | ((unsigned)f2bf(x1.y) << 16);
      u0.w = (unsigned)f2bf(x1.z) | ((unsigned)f2bf(x1.w) << 16);
      u1.x = (unsigned)f2bf(x2.x) | ((unsigned)f2bf(x2.y) << 16);
      u1.y = (unsigned)f2bf(x2.z) | ((unsigned)f2bf(x2.w) << 16);
      u1.z = (unsigned)f2bf(x3.x) | ((unsigned)f2bf(x3.y) << 16);
      u1.w = (unsigned)f2bf(x3.z) | ((unsigned)f2bf(x3.w) << 16);
      const int b0 = r * 256 + c0 * 2;
      const int sw = (r & 7) << 4;
      *(uint4*)((char*)Ks + (b0 ^ sw)) = u0;
      *(uint4*)((char*)Ks + ((b0 + 16) ^ sw)) = u1;
    }
    // ---- stage V tile transposed: thread covers rows r2,r2+1 x 8 cols ----
    {
      const int r2 = (tid & 15) * 2;     // 0..30
      const int c0 = (tid >> 4) * 8;     // 0..120
      const float* vp = Vg + base + (size_t)(t * NT + r2) * D_DIM + c0;
      float4 a0 = *(const float4*)(vp);
      float4 a1 = *(const float4*)(vp + 4);
      float4 b0 = *(const float4*)(vp + D_DIM);
      float4 b1 = *(const float4*)(vp + D_DIM + 4);
      unsigned w[8];
      w[0] = (unsigned)f2bf(a0.x) | ((unsigned)f2bf(b0.x) << 16);
      w[1] = (unsigned)f2bf(a0.y) | ((unsigned)f2bf(b0.y) << 16);
      w[2] = (unsigned)f2bf(a0.z) | ((unsigned)f2bf(b0.z) << 16);
      w[3] = (unsigned)f2bf(a0.w) | ((unsigned)f2bf(b0.w) << 16);
      w[4] = (unsigned)f2bf(a1.x) | ((unsigned)f2bf(b1.x) << 16);
      w[5] = (unsigned)f2bf(a1.y) | ((unsigned)f2bf(b1.y) << 16);
      w[6] = (unsigned)f2bf(a1.z) | ((unsigned)f2bf(b1.z) << 16);
      w[7] = (unsigned)f2bf(a1.w) | ((unsigned)f2bf(b1.w) << 16);
      char* vtb = (char*)Vt;
#pragma unroll
      for (int j = 0; j < 8; ++j)
        *(unsigned*)(vtb + (c0 + j) * 64 + r2 * 2) = w[j];
    }
    __syncthreads();

    // ---- S = Q K^T : two 16-key subtiles ----
    f32x4 s0 = zacc, s1 = zacc;
#pragma unroll
    for (int c = 0; c < 4; ++c) {
      int byte0 = ll * 256 + c * 64 + lg * 16;
      byte0 ^= (ll & 7) << 4;
      int byte1 = (ll + 16) * 256 + c * 64 + lg * 16;
      byte1 ^= (ll & 7) << 4;           // ((ll+16)&7) == (ll&7)
      short8 kb0 = *(const short8*)((const char*)Ks + byte0);
      short8 kb1 = *(const short8*)((const char*)Ks + byte1);
      s0 = __builtin_amdgcn_mfma_f32_16x16x32_bf16(qa[c], kb0, s0, 0, 0, 0);
      s1 = __builtin_amdgcn_mfma_f32_16x16x32_bf16(qa[c], kb1, s1, 0, 0, 0);
    }

    // ---- online softmax (rows live at reg r, kk across the 16-lane group) ----
    float alpha[4];
#pragma unroll
    for (int r = 0; r < 4; ++r) {
      float mx = fmaxf(s0[r], s1[r]);
#pragma unroll
      for (int off = 8; off > 0; off >>= 1) mx = fmaxf(mx, __shfl_xor(mx, off));
      float mn = fmaxf(mrow[r], mx);
      float al = __expf(mrow[r] - mn);
      float p0 = __expf(s0[r] - mn);
      float p1 = __expf(s1[r] - mn);
      float rs = p0 + p1;
#pragma unroll
      for (int off = 8; off > 0; off >>= 1) rs += __shfl_xor(rs, off);
      lrow[r] = lrow[r] * al + rs;
      mrow[r] = mn;
      alpha[r] = al;
      s0[r] = p0;
      s1[r] = p1;
    }

    // ---- P -> per-wave LDS (transpose to A-layout), rescale O ----
    unsigned short* myP = &Ps[wid][0];
#pragma unroll
    for (int r = 0; r < 4; ++r) {
      myP[(lg * 4 + r) * NT + ll]      = f2bf(s0[r]);
      myP[(lg * 4 + r) * NT + ll + 16] = f2bf(s1[r]);
    }
#pragma unroll
    for (int ds = 0; ds < 8; ++ds)
#pragma unroll
      for (int r = 0; r < 4; ++r) acc[ds][r] *= alpha[r];

    __builtin_amdgcn_wave_barrier();   // keep ds_write(P) before ds_read(P)
    short8 pa = *(const short8*)((const char*)myP + ll * 64 + lg * 16);

    // ---- O += P V ----
#pragma unroll
    for (int ds = 0; ds < 8; ++ds) {
      short8 vb = *(const short8*)((const char*)Vt + (ll + 16 * ds) * 64 + lg * 16);
      acc[ds] = __builtin_amdgcn_mfma_f32_16x16x32_bf16(pa, vb, acc[ds], 0, 0, 0);
    }
  }

  // ---- epilogue: O / l ----
  float* op = Og + base;
#pragma unroll
  for (int r = 0; r < 4; ++r) {
    const float inv = 1.0f / lrow[r];
    const int row = qt * QB + wid * 16 + lg * 4 + r;
#pragma unroll
    for (int ds = 0; ds < 8; ++ds)
      op[(size_t)row * D_DIM + ll + 16 * ds] = acc[ds][r] * inv;
  }
}

extern "C" void kernel_launch(void* const* d_in, const int* in_sizes, int n_in,
                              void* d_out, int out_size, void* d_ws, size_t ws_size,
                              hipStream_t stream) {
  const float* q = (const float*)d_in[0];
  const float* k = (const float*)d_in[1];
  const float* v = (const float*)d_in[2];
  float* out = (float*)d_out;
  const int grid = (2 * 16) * (S_LEN / QB);   // 32 bh * 32 q-tiles = 1024
  attn_fwd<<<grid, 256, 0, stream>>>(q, k, v, out);
}

// Round 2
// 129.413 us; speedup vs baseline: 2.4523x; 2.4523x over previous
//
#include <hip/hip_runtime.h>

#define S_LEN 2048
#define D_DIM 128
#define NBH   32
#define KVB   32            // keys per kv-tile
#define QW    32            // q rows per wave
#define NW    4             // waves per block
#define QB    (QW*NW)       // 128 q rows per block
#define NQT   (S_LEN/QB)    // 16 q-tiles
#define NT    (S_LEN/KVB)   // 64 kv-tiles

typedef __attribute__((ext_vector_type(8)))  short short8;
typedef __attribute__((ext_vector_type(16))) float f32x16;

__device__ __forceinline__ unsigned f2bf_u(float f) {
  union { float f; unsigned u; } x; x.f = f;
  x.u += 0x7FFFu + ((x.u >> 16) & 1u);   // RNE
  return x.u >> 16;
}
__device__ __forceinline__ unsigned pk2(float a, float b) {
  return f2bf_u(a) | (f2bf_u(b) << 16);
}

// fp32 -> bf16 stream converter (8 elems/thread, exact grid)
__global__ __launch_bounds__(256)
void cvt_bf16(const float* __restrict__ src, unsigned* __restrict__ dst) {
  const size_t i = (size_t)blockIdx.x * 256 + threadIdx.x;
  const float4* s = (const float4*)src + i * 2;
  float4 x0 = s[0], x1 = s[1];
  uint4 u;
  u.x = pk2(x0.x, x0.y); u.y = pk2(x0.z, x0.w);
  u.z = pk2(x1.x, x1.y); u.w = pk2(x1.z, x1.w);
  ((uint4*)dst)[i] = u;
}

// Flash attention, swapped-QK^T 32x32 structure.
// Score frag: s = mfma32x32x16(A=K, B=Q): col=lane&31 -> q (lane-local!),
//   row=(r&3)+8*(r>>2)+4*hw -> k. Softmax fully in-register.
// PV computed as O^T: acc[f] = mfma(A=V^T, B=P^T): col=q, row=d.
template<bool PRE>
__global__ __launch_bounds__(256, 2)
void attn_fwd(const float* __restrict__ Qf, const float* __restrict__ Kf,
              const float* __restrict__ Vf,
              const unsigned short* __restrict__ Kb,
              const unsigned short* __restrict__ Vb,
              float* __restrict__ Og) {
  // K tile [k][d] bf16, byte-XOR swizzle ((row&7)<<4); double buffered
  __shared__ __attribute__((aligned(16))) unsigned short Ks[2 * KVB * D_DIM];
  // V tile transposed [d][k] bf16, same row-XOR swizzle; double buffered
  __shared__ __attribute__((aligned(16))) unsigned short Vt[2 * D_DIM * KVB];

  const int tid  = threadIdx.x;
  const int lane = tid & 63;
  const int wid  = tid >> 6;
  const int l31  = lane & 31;
  const int hw   = lane >> 5;

  // XCD-grouped block swizzle: each XCD owns 4 whole (b,h) -> K/V L2-resident
  const int bid = blockIdx.x;
  const int bh  = (bid & 7) * 4 + ((bid >> 3) >> 4);
  const int qt  = (bid >> 3) & 15;
  const size_t base = (size_t)bh * (S_LEN * D_DIM);
  const int qrow = qt * QB + wid * QW + l31;

  // ---- Q fragments (B-operand): qb[c] elem e = Q[qrow][c*16 + hw*8 + e]
  short8 qb[8];
  {
    const float CS = 0.08838834764831845f * 1.44269504088896340f; // 1/sqrt(128)*log2e
    const float* qp = Qf + base + (size_t)qrow * D_DIM + hw * 8;
#pragma unroll
    for (int c = 0; c < 8; ++c) {
      float4 x0 = *(const float4*)(qp + c * 16);
      float4 x1 = *(const float4*)(qp + c * 16 + 4);
      union { unsigned u[4]; short8 v; } w;
      w.u[0] = pk2(x0.x * CS, x0.y * CS); w.u[1] = pk2(x0.z * CS, x0.w * CS);
      w.u[2] = pk2(x1.x * CS, x1.y * CS); w.u[3] = pk2(x1.z * CS, x1.w * CS);
      qb[c] = w.v;
    }
  }

  f32x16 acc[4];
#pragma unroll
  for (int f = 0; f < 4; ++f)
#pragma unroll
    for (int r = 0; r < 16; ++r) acc[f][r] = 0.f;
  float m = -3.0e38f, l = 0.f;

  // staging thread mapping
  const int kr = tid >> 3;         // K row 0..31
  const int kc = (tid & 7) << 4;   // K col (shorts)
  const int vr = (tid & 7) << 2;   // V rows r4 (k)
  const int vc = (tid >> 3) << 2;  // V cols c4 (d)

  uint4 Ku0, Ku1;    // prefetched K (packed bf16)
  unsigned Vw[8];    // prefetched Vt words: per j: (rows vr..vr+1 | vr+2..vr+3)

  auto LOAD = [&](int t) {
    if constexpr (PRE) {
      const unsigned short* kp = Kb + base + ((size_t)t * KVB + kr) * D_DIM + kc;
      Ku0 = *(const uint4*)kp; Ku1 = *(const uint4*)(kp + 8);
      const unsigned short* vp = Vb + base + ((size_t)t * KVB + vr) * D_DIM + vc;
      uint2 a0 = *(const uint2*)vp;
      uint2 a1 = *(const uint2*)(vp + D_DIM);
      uint2 a2 = *(const uint2*)(vp + 2 * D_DIM);
      uint2 a3 = *(const uint2*)(vp + 3 * D_DIM);
      Vw[0] = (a0.x & 0xFFFFu) | (a1.x << 16);
      Vw[1] = (a2.x & 0xFFFFu) | (a3.x << 16);
      Vw[2] = (a0.x >> 16) | (a1.x & 0xFFFF0000u);
      Vw[3] = (a2.x >> 16) | (a3.x & 0xFFFF0000u);
      Vw[4] = (a0.y & 0xFFFFu) | (a1.y << 16);
      Vw[5] = (a2.y & 0xFFFFu) | (a3.y << 16);
      Vw[6] = (a0.y >> 16) | (a1.y & 0xFFFF0000u);
      Vw[7] = (a2.y >> 16) | (a3.y & 0xFFFF0000u);
    } else {
      const float* kp = Kf + base + ((size_t)t * KVB + kr) * D_DIM + kc;
      float4 a = *(const float4*)kp,       b = *(const float4*)(kp + 4);
      float4 c = *(const float4*)(kp + 8), d = *(const float4*)(kp + 12);
      Ku0.x = pk2(a.x, a.y); Ku0.y = pk2(a.z, a.w);
      Ku0.z = pk2(b.x, b.y); Ku0.w = pk2(b.z, b.w);
      Ku1.x = pk2(c.x, c.y); Ku1.y = pk2(c.z, c.w);
      Ku1.z = pk2(d.x, d.y); Ku1.w = pk2(d.z, d.w);
      const float* vp = Vf + base + ((size_t)t * KVB + vr) * D_DIM + vc;
      float4 r0 = *(const float4*)vp;
      float4 r1 = *(const float4*)(vp + D_DIM);
      float4 r2 = *(const float4*)(vp + 2 * D_DIM);
      float4 r3 = *(const float4*)(vp + 3 * D_DIM);
      Vw[0] = pk2(r0.x, r1.x); Vw[1] = pk2(r2.x, r3.x);
      Vw[2] = pk2(r0.y, r1.y); Vw[3] = pk2(r2.y, r3.y);
      Vw[4] = pk2(r0.z, r1.z); Vw[5] = pk2(r2.z, r3.z);
      Vw[6] = pk2(r0.w, r1.w); Vw[7] = pk2(r2.w, r3.w);
    }
  };

  auto STORE = [&](int p) {
    char* kdst = (char*)(Ks + p * (KVB * D_DIM));
    const int b0 = kr * 256 + kc * 2;
    const int sw = (kr & 7) << 4;
    *(uint4*)(kdst + (b0 ^ sw)) = Ku0;
    *(uint4*)(kdst + ((b0 + 16) ^ sw)) = Ku1;
    char* vdst = (char*)(Vt + p * (D_DIM * KVB));
#pragma unroll
    for (int j = 0; j < 4; ++j) {
      const int d = vc + j;
      const int byte = (d * 64 + vr * 2) ^ ((d & 7) << 4);
      uint2 u; u.x = Vw[2 * j]; u.y = Vw[2 * j + 1];
      *(uint2*)(vdst + byte) = u;
    }
  };

  LOAD(0); STORE(0); __syncthreads();
  int p = 0;
  for (int t = 0; t < NT; ++t) {
    if (t + 1 < NT) LOAD(t + 1);     // HBM latency hides under compute (T14)

    const char* ksp = (const char*)(Ks + p * (KVB * D_DIM));
    const char* vtp = (const char*)(Vt + p * (D_DIM * KVB));
    const int asw = (l31 & 7) << 4;

    // ---- S^T = K Q^T ----
    f32x16 s;
#pragma unroll
    for (int r = 0; r < 16; ++r) s[r] = 0.f;
#pragma unroll
    for (int c = 0; c < 8; ++c) {
      const int byte = (l31 * 256 + c * 32 + hw * 16) ^ asw;
      short8 ka = *(const short8*)(ksp + byte);
      s = __builtin_amdgcn_mfma_f32_32x32x16_bf16(ka, qb[c], s, 0, 0, 0);
    }

    // ---- online softmax, fully in-register (q = l31 is lane-local) ----
    float pm = s[0];
#pragma unroll
    for (int r = 1; r < 16; ++r) pm = fmaxf(pm, s[r]);
    pm = fmaxf(pm, __shfl_xor(pm, 32));
    const float mn = fmaxf(m, pm);
    const float al = exp2f(m - mn);
    m = mn;
    float rs = 0.f;
#pragma unroll
    for (int r = 0; r < 16; ++r) { s[r] = exp2f(s[r] - mn); rs += s[r]; }
    rs += __shfl_xor(rs, 32);
    l = l * al + rs;

#pragma unroll
    for (int f = 0; f < 4; ++f)
#pragma unroll
      for (int r = 0; r < 16; ++r) acc[f][r] *= al;

    // ---- P^T -> bf16 B-frags (cvt_pk + permlane32_swap), then O^T += V^T P^T
    // Needed pb elem e (k = 16*t2 + 8*hw + e): from half (e>>2)'s reg
    // (e&3) + 8*t2 + 4*hw. permlane32_swap(Wlow,Whi) yields (W_j, W_{j+2}).
#pragma unroll
    for (int t2 = 0; t2 < 2; ++t2) {
      unsigned w0, w1, w2, w3;
      asm("v_cvt_pk_bf16_f32 %0, %1, %2" : "=v"(w0) : "v"(s[8*t2+0]), "v"(s[8*t2+1]));
      asm("v_cvt_pk_bf16_f32 %0, %1, %2" : "=v"(w1) : "v"(s[8*t2+2]), "v"(s[8*t2+3]));
      asm("v_cvt_pk_bf16_f32 %0, %1, %2" : "=v"(w2) : "v"(s[8*t2+4]), "v"(s[8*t2+5]));
      asm("v_cvt_pk_bf16_f32 %0, %1, %2" : "=v"(w3) : "v"(s[8*t2+6]), "v"(s[8*t2+7]));
      asm("v_permlane32_swap_b32 %0, %1" : "+v"(w0), "+v"(w2));
      asm("v_permlane32_swap_b32 %0, %1" : "+v"(w1), "+v"(w3));
      union { unsigned u[4]; short8 v; } pb;
      pb.u[0] = w0; pb.u[1] = w1; pb.u[2] = w2; pb.u[3] = w3;
#pragma unroll
      for (int f = 0; f < 4; ++f) {
        const int byte = ((32 * f + l31) * 64 + t2 * 32 + hw * 16) ^ asw;
        short8 va = *(const short8*)(vtp + byte);
        acc[f] = __builtin_amdgcn_mfma_f32_32x32x16_bf16(va, pb.v, acc[f], 0, 0, 0);
      }
    }

    if (t + 1 < NT) STORE(p ^ 1);
    __syncthreads();
    p ^= 1;
  }

  // ---- epilogue: O[q][d] = acc^T / l  (d = 32f + 8g + 4hw + j, j=0..3) ----
  const float inv = 1.0f / l;
  float* op = Og + base + (size_t)qrow * D_DIM;
#pragma unroll
  for (int f = 0; f < 4; ++f)
#pragma unroll
    for (int g = 0; g < 4; ++g) {
      float4 o;
      o.x = acc[f][4*g+0] * inv; o.y = acc[f][4*g+1] * inv;
      o.z = acc[f][4*g+2] * inv; o.w = acc[f][4*g+3] * inv;
      *(float4*)(op + 32 * f + 8 * g + 4 * hw) = o;
    }
}

extern "C" void kernel_launch(void* const* d_in, const int* in_sizes, int n_in,
                              void* d_out, int out_size, void* d_ws, size_t ws_size,
                              hipStream_t stream) {
  const float* q = (const float*)d_in[0];
  const float* k = (const float*)d_in[1];
  const float* v = (const float*)d_in[2];
  float* out = (float*)d_out;
  const size_t nel = (size_t)NBH * S_LEN * D_DIM;          // 8,388,608
  const size_t need = 2 * nel * sizeof(unsigned short);    // 32 MiB
  const int grid = NBH * NQT;                              // 512
  if (ws_size >= need) {
    unsigned short* kb = (unsigned short*)d_ws;
    unsigned short* vb = kb + nel;
    const int cgrid = (int)(nel / 8 / 256);                // 4096
    cvt_bf16<<<cgrid, 256, 0, stream>>>(k, (unsigned*)kb);
    cvt_bf16<<<cgrid, 256, 0, stream>>>(v, (unsigned*)vb);
    attn_fwd<true><<<grid, 256, 0, stream>>>(q, k, v, kb, vb, out);
  } else {
    attn_fwd<false><<<grid, 256, 0, stream>>>(q, k, v, nullptr, nullptr, out);
  }
}

// Round 3
// 128.390 us; speedup vs baseline: 2.4719x; 1.0080x over previous
//
#include <hip/hip_runtime.h>

#define S_LEN 2048
#define D_DIM 128
#define NBH   32
#define KVB   64            // keys per kv-tile
#define QW    32            // q rows per wave
#define NW    8             // waves per block
#define QB    (QW*NW)       // 256 q rows per block
#define NQT   (S_LEN/QB)    // 8 q-tiles
#define NT    (S_LEN/KVB)   // 32 kv-tiles

typedef __attribute__((ext_vector_type(8)))  short short8;
typedef __attribute__((ext_vector_type(16))) float f32x16;

__device__ __forceinline__ unsigned f2bf_u(float f) {
  union { float f; unsigned u; } x; x.f = f;
  x.u += 0x7FFFu + ((x.u >> 16) & 1u);   // RNE
  return x.u >> 16;
}
__device__ __forceinline__ unsigned pk2(float a, float b) {
  return f2bf_u(a) | (f2bf_u(b) << 16);
}

// fp32 -> bf16 stream converter (8 elems/thread)
__global__ __launch_bounds__(256)
void cvt_bf16(const float* __restrict__ src, unsigned* __restrict__ dst) {
  const size_t i = (size_t)blockIdx.x * 256 + threadIdx.x;
  const float4* s = (const float4*)src + i * 2;
  float4 x0 = s[0], x1 = s[1];
  uint4 u;
  u.x = pk2(x0.x, x0.y); u.y = pk2(x0.z, x0.w);
  u.z = pk2(x1.x, x1.y); u.w = pk2(x1.z, x1.w);
  ((uint4*)dst)[i] = u;
}

// Flash attention, swapped-QK^T 32x32 structure, 8 waves x 32 q-rows.
// Score frag s = mfma32x32x16(A=K, B=Q): col(lane&31)=q (lane-local),
//   row=(r&3)+8*(r>>2)+4*hw = k. Softmax fully in-register, defer-max (T13).
// PV as O^T: acc[f] = mfma(A=V^T, B=P^T): col=q, row=d.
template<bool PRE>
__global__ __launch_bounds__(512, 2)
void attn_fwd(const float* __restrict__ Qf, const float* __restrict__ Kf,
              const float* __restrict__ Vf,
              const unsigned short* __restrict__ Kb,
              const unsigned short* __restrict__ Vb,
              float* __restrict__ Og) {
  // K tile [k][d] bf16, byte-XOR swizzle ((row&7)<<4); double buffered (32KB)
  __shared__ __attribute__((aligned(16))) unsigned short Ks[2 * KVB * D_DIM];
  // V tile transposed [d][k] bf16, row-XOR swizzle; double buffered (32KB)
  __shared__ __attribute__((aligned(16))) unsigned short Vt[2 * D_DIM * KVB];

  const int tid  = threadIdx.x;
  const int lane = tid & 63;
  const int wid  = tid >> 6;
  const int l31  = lane & 31;
  const int hw   = lane >> 5;

  // XCD-grouped swizzle: grid 256, 8 XCDs round-robin on bid&7 -> give each
  // XCD 4 whole (b,h) so K/V stay L2-resident per XCD.
  const int bid = blockIdx.x;
  const int bh  = (bid & 7) * 4 + ((bid >> 3) >> 3);
  const int qt  = (bid >> 3) & 7;
  const size_t base = (size_t)bh * (S_LEN * D_DIM);
  const int qrow = qt * QB + wid * QW + l31;

  // ---- Q fragments (B-operand): qb[c] elem e = Q[qrow][c*16 + hw*8 + e]
  short8 qb[8];
  {
    const float CS = 0.08838834764831845f * 1.44269504088896340f; // rsqrt(128)*log2e
    const float* qp = Qf + base + (size_t)qrow * D_DIM + hw * 8;
#pragma unroll
    for (int c = 0; c < 8; ++c) {
      float4 x0 = *(const float4*)(qp + c * 16);
      float4 x1 = *(const float4*)(qp + c * 16 + 4);
      union { unsigned u[4]; short8 v; } w;
      w.u[0] = pk2(x0.x * CS, x0.y * CS); w.u[1] = pk2(x0.z * CS, x0.w * CS);
      w.u[2] = pk2(x1.x * CS, x1.y * CS); w.u[3] = pk2(x1.z * CS, x1.w * CS);
      qb[c] = w.v;
    }
  }

  f32x16 acc[4];
#pragma unroll
  for (int f = 0; f < 4; ++f)
#pragma unroll
    for (int r = 0; r < 16; ++r) acc[f][r] = 0.f;
  float m = -3.0e38f, l = 0.f;

  // staging thread mapping (512 threads)
  const int kr = tid >> 3;         // K row 0..63
  const int kc = (tid & 7) << 4;   // K col shorts 0..112
  const int vr = (tid & 15) << 2;  // V k-rows vr..vr+3
  const int vc = (tid >> 4) << 2;  // V d-cols vc..vc+3

  uint4 Ku0, Ku1;
  unsigned Vw[8];

  const unsigned short* kp = PRE ? (Kb + base + (size_t)kr * D_DIM + kc) : nullptr;
  const unsigned short* vp = PRE ? (Vb + base + (size_t)vr * D_DIM + vc) : nullptr;
  const float* kpf = PRE ? nullptr : (Kf + base + (size_t)kr * D_DIM + kc);
  const float* vpf = PRE ? nullptr : (Vf + base + (size_t)vr * D_DIM + vc);

  auto LOAD = [&]() {
    if constexpr (PRE) {
      Ku0 = *(const uint4*)kp; Ku1 = *(const uint4*)(kp + 8);
      uint2 a0 = *(const uint2*)vp;
      uint2 a1 = *(const uint2*)(vp + D_DIM);
      uint2 a2 = *(const uint2*)(vp + 2 * D_DIM);
      uint2 a3 = *(const uint2*)(vp + 3 * D_DIM);
      Vw[0] = (a0.x & 0xFFFFu) | (a1.x << 16);
      Vw[1] = (a2.x & 0xFFFFu) | (a3.x << 16);
      Vw[2] = (a0.x >> 16) | (a1.x & 0xFFFF0000u);
      Vw[3] = (a2.x >> 16) | (a3.x & 0xFFFF0000u);
      Vw[4] = (a0.y & 0xFFFFu) | (a1.y << 16);
      Vw[5] = (a2.y & 0xFFFFu) | (a3.y << 16);
      Vw[6] = (a0.y >> 16) | (a1.y & 0xFFFF0000u);
      Vw[7] = (a2.y >> 16) | (a3.y & 0xFFFF0000u);
      kp += (size_t)KVB * D_DIM; vp += (size_t)KVB * D_DIM;
    } else {
      float4 a = *(const float4*)kpf,        b = *(const float4*)(kpf + 4);
      float4 c = *(const float4*)(kpf + 8),  d = *(const float4*)(kpf + 12);
      Ku0.x = pk2(a.x, a.y); Ku0.y = pk2(a.z, a.w);
      Ku0.z = pk2(b.x, b.y); Ku0.w = pk2(b.z, b.w);
      Ku1.x = pk2(c.x, c.y); Ku1.y = pk2(c.z, c.w);
      Ku1.z = pk2(d.x, d.y); Ku1.w = pk2(d.z, d.w);
      float4 r0 = *(const float4*)vpf;
      float4 r1 = *(const float4*)(vpf + D_DIM);
      float4 r2 = *(const float4*)(vpf + 2 * D_DIM);
      float4 r3 = *(const float4*)(vpf + 3 * D_DIM);
      Vw[0] = pk2(r0.x, r1.x); Vw[1] = pk2(r2.x, r3.x);
      Vw[2] = pk2(r0.y, r1.y); Vw[3] = pk2(r2.y, r3.y);
      Vw[4] = pk2(r0.z, r1.z); Vw[5] = pk2(r2.z, r3.z);
      Vw[6] = pk2(r0.w, r1.w); Vw[7] = pk2(r2.w, r3.w);
      kpf += (size_t)KVB * D_DIM; vpf += (size_t)KVB * D_DIM;
    }
  };

  auto STORE = [&](int p) {
    char* kdst = (char*)(Ks + p * (KVB * D_DIM));
    const int b0 = kr * 256 + kc * 2;
    const int sw = (kr & 7) << 4;
    *(uint4*)(kdst + (b0 ^ sw)) = Ku0;
    *(uint4*)(kdst + ((b0 + 16) ^ sw)) = Ku1;
    char* vdst = (char*)(Vt + p * (D_DIM * KVB));
#pragma unroll
    for (int j = 0; j < 4; ++j) {
      const int d = vc + j;
      const int byte = (d * 128 + vr * 2) ^ ((d & 7) << 4);
      uint2 u; u.x = Vw[2 * j]; u.y = Vw[2 * j + 1];
      *(uint2*)(vdst + byte) = u;
    }
  };

  LOAD(); STORE(0); __syncthreads();
  int p = 0;
  for (int t = 0; t < NT; ++t) {
    if (t + 1 < NT) LOAD();          // issue next-tile loads early (T14)

    const char* ksp = (const char*)(Ks + p * (KVB * D_DIM));
    const char* vtp = (const char*)(Vt + p * (D_DIM * KVB));
    const int asw = (l31 & 7) << 4;

    // ---- S^T = K Q^T (two 32-key subtiles) ----
    f32x16 s0, s1;
#pragma unroll
    for (int r = 0; r < 16; ++r) { s0[r] = 0.f; s1[r] = 0.f; }
    __builtin_amdgcn_s_setprio(1);
#pragma unroll
    for (int c = 0; c < 8; ++c) {
      const int byte = (l31 * 256 + c * 32 + hw * 16) ^ asw;
      short8 ka0 = *(const short8*)(ksp + byte);
      short8 ka1 = *(const short8*)(ksp + byte + 8192);
      s0 = __builtin_amdgcn_mfma_f32_32x32x16_bf16(ka0, qb[c], s0, 0, 0, 0);
      s1 = __builtin_amdgcn_mfma_f32_32x32x16_bf16(ka1, qb[c], s1, 0, 0, 0);
    }
    __builtin_amdgcn_s_setprio(0);

    // ---- online softmax with defer-max (T13, THR=8 in log2 units) ----
    float pm = s0[0];
#pragma unroll
    for (int r = 1; r < 16; ++r) pm = fmaxf(pm, s0[r]);
#pragma unroll
    for (int r = 0; r < 16; ++r) pm = fmaxf(pm, s1[r]);
    pm = fmaxf(pm, __shfl_xor(pm, 32));
    if (!__all(pm - m <= 8.f)) {
      const float mn = fmaxf(m, pm);
      const float al = exp2f(m - mn);
      m = mn; l *= al;
#pragma unroll
      for (int f = 0; f < 4; ++f)
#pragma unroll
        for (int r = 0; r < 16; ++r) acc[f][r] *= al;
    }
    float rs = 0.f;
#pragma unroll
    for (int r = 0; r < 16; ++r) { s0[r] = exp2f(s0[r] - m); rs += s0[r]; }
#pragma unroll
    for (int r = 0; r < 16; ++r) { s1[r] = exp2f(s1[r] - m); rs += s1[r]; }
    rs += __shfl_xor(rs, 32);
    l += rs;

    // ---- P^T -> bf16 B-frags (cvt_pk + permlane32_swap); O^T += V^T P^T ----
    // pb elem e (k = 16*t2 + 8*hw + e) comes from score reg (e&3)+8*(t2&1)+4*hw
    // of s0 (t2<2) / s1 (t2>=2), source lane-half e>>2 (permlane32_swap).
#pragma unroll
    for (int t2 = 0; t2 < 4; ++t2) {
      unsigned w0, w1, w2, w3;
      if (t2 < 2) {
        const int rb = 8 * t2;
        asm("v_cvt_pk_bf16_f32 %0, %1, %2" : "=v"(w0) : "v"(s0[rb+0]), "v"(s0[rb+1]));
        asm("v_cvt_pk_bf16_f32 %0, %1, %2" : "=v"(w1) : "v"(s0[rb+2]), "v"(s0[rb+3]));
        asm("v_cvt_pk_bf16_f32 %0, %1, %2" : "=v"(w2) : "v"(s0[rb+4]), "v"(s0[rb+5]));
        asm("v_cvt_pk_bf16_f32 %0, %1, %2" : "=v"(w3) : "v"(s0[rb+6]), "v"(s0[rb+7]));
      } else {
        const int rb = 8 * (t2 - 2);
        asm("v_cvt_pk_bf16_f32 %0, %1, %2" : "=v"(w0) : "v"(s1[rb+0]), "v"(s1[rb+1]));
        asm("v_cvt_pk_bf16_f32 %0, %1, %2" : "=v"(w1) : "v"(s1[rb+2]), "v"(s1[rb+3]));
        asm("v_cvt_pk_bf16_f32 %0, %1, %2" : "=v"(w2) : "v"(s1[rb+4]), "v"(s1[rb+5]));
        asm("v_cvt_pk_bf16_f32 %0, %1, %2" : "=v"(w3) : "v"(s1[rb+6]), "v"(s1[rb+7]));
      }
      asm("v_permlane32_swap_b32 %0, %1" : "+v"(w0), "+v"(w2));
      asm("v_permlane32_swap_b32 %0, %1" : "+v"(w1), "+v"(w3));
      union { unsigned u[4]; short8 v; } pb;
      pb.u[0] = w0; pb.u[1] = w1; pb.u[2] = w2; pb.u[3] = w3;
      __builtin_amdgcn_s_setprio(1);
#pragma unroll
      for (int f = 0; f < 4; ++f) {
        const int byte = ((32 * f + l31) * 128 + t2 * 32 + hw * 16) ^ asw;
        short8 va = *(const short8*)(vtp + byte);
        acc[f] = __builtin_amdgcn_mfma_f32_32x32x16_bf16(va, pb.v, acc[f], 0, 0, 0);
      }
      __builtin_amdgcn_s_setprio(0);
    }

    if (t + 1 < NT) STORE(p ^ 1);
    __syncthreads();
    p ^= 1;
  }

  // ---- epilogue: O[q][d] = acc^T / l  (d = 32f + 8g + 4hw + j) ----
  const float inv = 1.0f / l;
  float* op = Og + base + (size_t)qrow * D_DIM;
#pragma unroll
  for (int f = 0; f < 4; ++f)
#pragma unroll
    for (int g = 0; g < 4; ++g) {
      float4 o;
      o.x = acc[f][4*g+0] * inv; o.y = acc[f][4*g+1] * inv;
      o.z = acc[f][4*g+2] * inv; o.w = acc[f][4*g+3] * inv;
      *(float4*)(op + 32 * f + 8 * g + 4 * hw) = o;
    }
}

extern "C" void kernel_launch(void* const* d_in, const int* in_sizes, int n_in,
                              void* d_out, int out_size, void* d_ws, size_t ws_size,
                              hipStream_t stream) {
  const float* q = (const float*)d_in[0];
  const float* k = (const float*)d_in[1];
  const float* v = (const float*)d_in[2];
  float* out = (float*)d_out;
  const size_t nel = (size_t)NBH * S_LEN * D_DIM;          // 8,388,608
  const size_t need = 2 * nel * sizeof(unsigned short);    // 32 MiB
  const int grid = NBH * NQT;                              // 256
  if (ws_size >= need) {
    unsigned short* kb = (unsigned short*)d_ws;
    unsigned short* vb = kb + nel;
    const int cgrid = (int)(nel / 8 / 256);                // 4096
    cvt_bf16<<<cgrid, 256, 0, stream>>>(k, (unsigned*)kb);
    cvt_bf16<<<cgrid, 256, 0, stream>>>(v, (unsigned*)vb);
    attn_fwd<true><<<grid, 512, 0, stream>>>(q, k, v, kb, vb, out);
  } else {
    attn_fwd<false><<<grid, 512, 0, stream>>>(q, k, v, nullptr, nullptr, out);
  }
}

// Round 6
// 112.860 us; speedup vs baseline: 2.8120x; 1.1376x over previous
//
#include <hip/hip_runtime.h>

#define S_LEN 2048
#define D_DIM 128
#define NBH   32
#define KVB   64            // keys per kv-tile
#define QW    32            // q rows per wave
#define NW    8             // waves per block
#define QB    (QW*NW)       // 256 q rows per block
#define NQT   (S_LEN/QB)    // 8 q-tiles
#define NT    (S_LEN/KVB)   // 32 kv-tiles

typedef __attribute__((ext_vector_type(8)))  short short8;
typedef __attribute__((ext_vector_type(16))) float f32x16;

__device__ __forceinline__ unsigned f2bf_u(float f) {
  union { float f; unsigned u; } x; x.f = f;
  x.u += 0x7FFFu + ((x.u >> 16) & 1u);   // RNE
  return x.u >> 16;
}
__device__ __forceinline__ unsigned pk2(float a, float b) {
  return f2bf_u(a) | (f2bf_u(b) << 16);
}

// NOTE (R4/R5 post-mortem): hand-rolled cross-half reduction via
// v_permlane32_swap inline asm failed twice (copy-coalesced self-swap in R4;
// in-asm write->permlane-read hazard in R5). The l-sum is the one softmax
// quantity that does NOT cancel in O = acc/l, so it must be bulletproof.
// Use the R3-proven __shfl_xor(x,32) here. The P-path permlane asm below is
// proven correct (R2/R3) — its operands are written several instrs before use.

// fp32 -> bf16 stream converter (8 elems/thread)
__global__ __launch_bounds__(256)
void cvt_bf16(const float* __restrict__ src, unsigned* __restrict__ dst) {
  const size_t i = (size_t)blockIdx.x * 256 + threadIdx.x;
  const float4* s = (const float4*)src + i * 2;
  float4 x0 = s[0], x1 = s[1];
  uint4 u;
  u.x = pk2(x0.x, x0.y); u.y = pk2(x0.z, x0.w);
  u.z = pk2(x1.x, x1.y); u.w = pk2(x1.z, x1.w);
  ((uint4*)dst)[i] = u;
}

// Flash attention, swapped-QK^T 32x32 structure, 8 waves x 32 q-rows.
// Score frag s = mfma32x32x16(A=K, B=Q): col(lane&31)=q (lane-local),
//   row=(r&3)+8*(r>>2)+4*hw = k. Softmax fully in-register, defer-max (T13).
// PV as O^T: acc[f] = mfma(A=V^T, B=P^T): col=q, row=d.
// Staging is async-split (T14): LOAD = pure global loads issued before
// compute; STORE = repack + ds_write after compute (vmcnt wait hidden).
template<bool PRE>
__global__ __launch_bounds__(512, 2)
void attn_fwd(const float* __restrict__ Qf, const float* __restrict__ Kf,
              const float* __restrict__ Vf,
              const unsigned short* __restrict__ Kb,
              const unsigned short* __restrict__ Vb,
              float* __restrict__ Og) {
  // K tile [k][d] bf16, byte-XOR swizzle ((row&7)<<4); double buffered (32KB)
  __shared__ __attribute__((aligned(16))) unsigned short Ks[2 * KVB * D_DIM];
  // V tile transposed [d][k] bf16, row-XOR swizzle; double buffered (32KB)
  __shared__ __attribute__((aligned(16))) unsigned short Vt[2 * D_DIM * KVB];

  const int tid  = threadIdx.x;
  const int lane = tid & 63;
  const int wid  = tid >> 6;
  const int l31  = lane & 31;
  const int hw   = lane >> 5;

  // XCD-grouped swizzle: each XCD owns 4 whole (b,h) -> K/V L2-resident.
  const int bid = blockIdx.x;
  const int bh  = (bid & 7) * 4 + ((bid >> 3) >> 3);
  const int qt  = (bid >> 3) & 7;
  const size_t base = (size_t)bh * (S_LEN * D_DIM);
  const int qrow = qt * QB + wid * QW + l31;

  // ---- Q fragments (B-operand): qb[c] elem e = Q[qrow][c*16 + hw*8 + e]
  short8 qb[8];
  {
    const float CS = 0.08838834764831845f * 1.44269504088896340f; // rsqrt(128)*log2e
    const float* qp = Qf + base + (size_t)qrow * D_DIM + hw * 8;
#pragma unroll
    for (int c = 0; c < 8; ++c) {
      float4 x0 = *(const float4*)(qp + c * 16);
      float4 x1 = *(const float4*)(qp + c * 16 + 4);
      union { unsigned u[4]; short8 v; } w;
      w.u[0] = pk2(x0.x * CS, x0.y * CS); w.u[1] = pk2(x0.z * CS, x0.w * CS);
      w.u[2] = pk2(x1.x * CS, x1.y * CS); w.u[3] = pk2(x1.z * CS, x1.w * CS);
      qb[c] = w.v;
    }
  }

  f32x16 acc[4];
#pragma unroll
  for (int f = 0; f < 4; ++f)
#pragma unroll
    for (int r = 0; r < 16; ++r) acc[f][r] = 0.f;
  float m = -3.0e38f, l = 0.f;

  // staging thread mapping (512 threads)
  const int kr = tid >> 3;         // K row 0..63
  const int kc = (tid & 7) << 4;   // K col shorts 0..112
  const int vr = (tid & 15) << 2;  // V k-rows vr..vr+3
  const int vc = (tid >> 4) << 2;  // V d-cols vc..vc+3

  // raw prefetch registers (no dependent ops until STORE)
  uint4  Ku0, Ku1;                 // PRE: K bf16 raw
  uint2  Va0, Va1, Va2, Va3;       // PRE: V bf16 raw rows
  float4 Kf0, Kf1, Kf2, Kf3;       // fallback fp32 raw
  float4 Vf0, Vf1, Vf2, Vf3;

  const unsigned short* kp = PRE ? (Kb + base + (size_t)kr * D_DIM + kc) : nullptr;
  const unsigned short* vp = PRE ? (Vb + base + (size_t)vr * D_DIM + vc) : nullptr;
  const float* kpf = PRE ? nullptr : (Kf + base + (size_t)kr * D_DIM + kc);
  const float* vpf = PRE ? nullptr : (Vf + base + (size_t)vr * D_DIM + vc);

  auto LOAD = [&]() {   // pure loads, no dependent ALU
    if constexpr (PRE) {
      Ku0 = *(const uint4*)kp; Ku1 = *(const uint4*)(kp + 8);
      Va0 = *(const uint2*)vp;
      Va1 = *(const uint2*)(vp + D_DIM);
      Va2 = *(const uint2*)(vp + 2 * D_DIM);
      Va3 = *(const uint2*)(vp + 3 * D_DIM);
      kp += (size_t)KVB * D_DIM; vp += (size_t)KVB * D_DIM;
    } else {
      Kf0 = *(const float4*)kpf;        Kf1 = *(const float4*)(kpf + 4);
      Kf2 = *(const float4*)(kpf + 8);  Kf3 = *(const float4*)(kpf + 12);
      Vf0 = *(const float4*)vpf;
      Vf1 = *(const float4*)(vpf + D_DIM);
      Vf2 = *(const float4*)(vpf + 2 * D_DIM);
      Vf3 = *(const float4*)(vpf + 3 * D_DIM);
      kpf += (size_t)KVB * D_DIM; vpf += (size_t)KVB * D_DIM;
    }
  };

  auto STORE = [&](int p) {   // repack + LDS write (waits live here, hidden)
    uint4 k0, k1;
    unsigned Vw[8];
    if constexpr (PRE) {
      k0 = Ku0; k1 = Ku1;
      Vw[0] = (Va0.x & 0xFFFFu) | (Va1.x << 16);
      Vw[1] = (Va2.x & 0xFFFFu) | (Va3.x << 16);
      Vw[2] = (Va0.x >> 16) | (Va1.x & 0xFFFF0000u);
      Vw[3] = (Va2.x >> 16) | (Va3.x & 0xFFFF0000u);
      Vw[4] = (Va0.y & 0xFFFFu) | (Va1.y << 16);
      Vw[5] = (Va2.y & 0xFFFFu) | (Va3.y << 16);
      Vw[6] = (Va0.y >> 16) | (Va1.y & 0xFFFF0000u);
      Vw[7] = (Va2.y >> 16) | (Va3.y & 0xFFFF0000u);
    } else {
      k0.x = pk2(Kf0.x, Kf0.y); k0.y = pk2(Kf0.z, Kf0.w);
      k0.z = pk2(Kf1.x, Kf1.y); k0.w = pk2(Kf1.z, Kf1.w);
      k1.x = pk2(Kf2.x, Kf2.y); k1.y = pk2(Kf2.z, Kf2.w);
      k1.z = pk2(Kf3.x, Kf3.y); k1.w = pk2(Kf3.z, Kf3.w);
      Vw[0] = pk2(Vf0.x, Vf1.x); Vw[1] = pk2(Vf2.x, Vf3.x);
      Vw[2] = pk2(Vf0.y, Vf1.y); Vw[3] = pk2(Vf2.y, Vf3.y);
      Vw[4] = pk2(Vf0.z, Vf1.z); Vw[5] = pk2(Vf2.z, Vf3.z);
      Vw[6] = pk2(Vf0.w, Vf1.w); Vw[7] = pk2(Vf2.w, Vf3.w);
    }
    char* kdst = (char*)(Ks + p * (KVB * D_DIM));
    const int b0 = kr * 256 + kc * 2;
    const int sw = (kr & 7) << 4;
    *(uint4*)(kdst + (b0 ^ sw)) = k0;
    *(uint4*)(kdst + ((b0 + 16) ^ sw)) = k1;
    char* vdst = (char*)(Vt + p * (D_DIM * KVB));
#pragma unroll
    for (int j = 0; j < 4; ++j) {
      const int d = vc + j;
      const int byte = (d * 128 + vr * 2) ^ ((d & 7) << 4);
      uint2 u; u.x = Vw[2 * j]; u.y = Vw[2 * j + 1];
      *(uint2*)(vdst + byte) = u;
    }
  };

  LOAD(); STORE(0); __syncthreads();
  int p = 0;
  for (int t = 0; t < NT; ++t) {
    if (t + 1 < NT) LOAD();          // issue next-tile loads (pure, async)

    const char* ksp = (const char*)(Ks + p * (KVB * D_DIM));
    const char* vtp = (const char*)(Vt + p * (D_DIM * KVB));
    const int asw = (l31 & 7) << 4;

    // ---- S^T = K Q^T (two 32-key subtiles) ----
    f32x16 s0, s1;
#pragma unroll
    for (int r = 0; r < 16; ++r) { s0[r] = 0.f; s1[r] = 0.f; }
    __builtin_amdgcn_s_setprio(1);
#pragma unroll
    for (int c = 0; c < 8; ++c) {
      const int byte = (l31 * 256 + c * 32 + hw * 16) ^ asw;
      short8 ka0 = *(const short8*)(ksp + byte);
      short8 ka1 = *(const short8*)(ksp + byte + 8192);
      s0 = __builtin_amdgcn_mfma_f32_32x32x16_bf16(ka0, qb[c], s0, 0, 0, 0);
      s1 = __builtin_amdgcn_mfma_f32_32x32x16_bf16(ka1, qb[c], s1, 0, 0, 0);
    }
    __builtin_amdgcn_s_setprio(0);

    // ---- online softmax: tree max, defer-max (T13, THR=8 log2 units) ----
    float tm[16];
#pragma unroll
    for (int r = 0; r < 16; ++r) tm[r] = fmaxf(s0[r], s1[r]);
#pragma unroll
    for (int st = 8; st > 0; st >>= 1)
#pragma unroll
      for (int r = 0; r < st; ++r) tm[r] = fmaxf(tm[r], tm[r + st]);
    const float pm = fmaxf(tm[0], __shfl_xor(tm[0], 32));
    if (!__all(pm - m <= 8.f)) {
      const float mn = fmaxf(m, pm);
      const float al = exp2f(m - mn);
      m = mn; l *= al;
#pragma unroll
      for (int f = 0; f < 4; ++f)
#pragma unroll
        for (int r = 0; r < 16; ++r) acc[f][r] *= al;
    }
    float ts[16];
#pragma unroll
    for (int r = 0; r < 16; ++r) {
      s0[r] = exp2f(s0[r] - m);
      s1[r] = exp2f(s1[r] - m);
      ts[r] = s0[r] + s1[r];
    }
#pragma unroll
    for (int st = 8; st > 0; st >>= 1)
#pragma unroll
      for (int r = 0; r < st; ++r) ts[r] += ts[r + st];
    l += ts[0] + __shfl_xor(ts[0], 32);

    // ---- P^T -> bf16 B-frags (cvt_pk + permlane32_swap); O^T += V^T P^T ----
    // pb elem e (k = 16*t2 + 8*hw + e) comes from score reg (e&3)+8*(t2&1)+4*hw
    // of s0 (t2<2) / s1 (t2>=2), source lane-half e>>2 (permlane32_swap).
#pragma unroll
    for (int t2 = 0; t2 < 4; ++t2) {
      unsigned w0, w1, w2, w3;
      if (t2 < 2) {
        const int rb = 8 * t2;
        asm("v_cvt_pk_bf16_f32 %0, %1, %2" : "=v"(w0) : "v"(s0[rb+0]), "v"(s0[rb+1]));
        asm("v_cvt_pk_bf16_f32 %0, %1, %2" : "=v"(w1) : "v"(s0[rb+2]), "v"(s0[rb+3]));
        asm("v_cvt_pk_bf16_f32 %0, %1, %2" : "=v"(w2) : "v"(s0[rb+4]), "v"(s0[rb+5]));
        asm("v_cvt_pk_bf16_f32 %0, %1, %2" : "=v"(w3) : "v"(s0[rb+6]), "v"(s0[rb+7]));
      } else {
        const int rb = 8 * (t2 - 2);
        asm("v_cvt_pk_bf16_f32 %0, %1, %2" : "=v"(w0) : "v"(s1[rb+0]), "v"(s1[rb+1]));
        asm("v_cvt_pk_bf16_f32 %0, %1, %2" : "=v"(w1) : "v"(s1[rb+2]), "v"(s1[rb+3]));
        asm("v_cvt_pk_bf16_f32 %0, %1, %2" : "=v"(w2) : "v"(s1[rb+4]), "v"(s1[rb+5]));
        asm("v_cvt_pk_bf16_f32 %0, %1, %2" : "=v"(w3) : "v"(s1[rb+6]), "v"(s1[rb+7]));
      }
      asm("v_permlane32_swap_b32 %0, %1" : "+v"(w0), "+v"(w2));
      asm("v_permlane32_swap_b32 %0, %1" : "+v"(w1), "+v"(w3));
      union { unsigned u[4]; short8 v; } pb;
      pb.u[0] = w0; pb.u[1] = w1; pb.u[2] = w2; pb.u[3] = w3;
      __builtin_amdgcn_s_setprio(1);
#pragma unroll
      for (int f = 0; f < 4; ++f) {
        const int byte = ((32 * f + l31) * 128 + t2 * 32 + hw * 16) ^ asw;
        short8 va = *(const short8*)(vtp + byte);
        acc[f] = __builtin_amdgcn_mfma_f32_32x32x16_bf16(va, pb.v, acc[f], 0, 0, 0);
      }
      __builtin_amdgcn_s_setprio(0);
    }

    if (t + 1 < NT) STORE(p ^ 1);    // vmcnt wait lands here, hidden
    __syncthreads();
    p ^= 1;
  }

  // ---- epilogue: O[q][d] = acc^T / l  (d = 32f + 8g + 4hw + j) ----
  const float inv = 1.0f / l;
  float* op = Og + base + (size_t)qrow * D_DIM;
#pragma unroll
  for (int f = 0; f < 4; ++f)
#pragma unroll
    for (int g = 0; g < 4; ++g) {
      float4 o;
      o.x = acc[f][4*g+0] * inv; o.y = acc[f][4*g+1] * inv;
      o.z = acc[f][4*g+2] * inv; o.w = acc[f][4*g+3] * inv;
      *(float4*)(op + 32 * f + 8 * g + 4 * hw) = o;
    }
}

extern "C" void kernel_launch(void* const* d_in, const int* in_sizes, int n_in,
                              void* d_out, int out_size, void* d_ws, size_t ws_size,
                              hipStream_t stream) {
  const float* q = (const float*)d_in[0];
  const float* k = (const float*)d_in[1];
  const float* v = (const float*)d_in[2];
  float* out = (float*)d_out;
  const size_t nel = (size_t)NBH * S_LEN * D_DIM;          // 8,388,608
  const size_t need = 2 * nel * sizeof(unsigned short);    // 32 MiB
  const int grid = NBH * NQT;                              // 256
  if (ws_size >= need) {
    unsigned short* kb = (unsigned short*)d_ws;
    unsigned short* vb = kb + nel;
    const int cgrid = (int)(nel / 8 / 256);                // 4096
    cvt_bf16<<<cgrid, 256, 0, stream>>>(k, (unsigned*)kb);
    cvt_bf16<<<cgrid, 256, 0, stream>>>(v, (unsigned*)vb);
    attn_fwd<true><<<grid, 512, 0, stream>>>(q, k, v, kb, vb, out);
  } else {
    attn_fwd<false><<<grid, 512, 0, stream>>>(q, k, v, nullptr, nullptr, out);
  }
}